// Round 12
// baseline (850.176 us; speedup 1.0000x reference)
//
#include <hip/hip_runtime.h>

#define U_NUM   100000
#define I_NUM   50000
#define FCT     64
#define NEDGE   3200000
#define BATCH   16384
#define NROWS   (U_NUM + I_NUM)      // 150000
#define TOTSLOTS (2 * NEDGE)         // 6400000

#define BSH 6                        // 64 rows per bucket
#define NBU 1563                     // ceil(100000/64)
#define NBI 782                      // ceil(50000/64)
#define NBUCK (NBU + NBI)            // 2345
#define NQ   294                     // ceil(NBUCK/8) buckets per class
#define SUBS 256                     // blocks per class in scatter grid
#define BUFSZ 4096                   // LDS payload buffer (expected fill 3125)

__device__ __forceinline__ unsigned short f2b(float f) {
    unsigned int x = __float_as_uint(f);
    unsigned int r = (x + 0x7FFFu + ((x >> 16) & 1u)) >> 16;   // RNE
    return (unsigned short)r;
}
__device__ __forceinline__ float b2f(unsigned short u) {
    return __uint_as_float(((unsigned int)u) << 16);
}

// ---------------- fp32 -> bf16 table conversion ----------------
__global__ void conv_kernel(const float* __restrict__ in, unsigned short* __restrict__ out, int n4) {
    int t = blockIdx.x * blockDim.x + threadIdx.x;
    if (t >= n4) return;
    float4 v = *reinterpret_cast<const float4*>(in + (size_t)t * 4);
    ushort4 o;
    o.x = f2b(v.x); o.y = f2b(v.y); o.z = f2b(v.z); o.w = f2b(v.w);
    *reinterpret_cast<ushort4*>(out + (size_t)t * 4) = o;
}

// ---------------- bucket histogram: LDS-private count, flush to class copy ----------------
__global__ void __launch_bounds__(256) bhist_kernel(const int* __restrict__ eu,
                                                    const int* __restrict__ ei,
                                                    int* __restrict__ bcnt8) {
    __shared__ int lcnt[NBUCK];
    for (int k = threadIdx.x; k < NBUCK; k += 256) lcnt[k] = 0;
    __syncthreads();
    int stride = gridDim.x * 256;
    for (int t = blockIdx.x * 256 + (int)threadIdx.x; t < NEDGE; t += stride) {
        int u = eu[t];
        int i = ei[t];
        atomicAdd(&lcnt[u >> BSH], 1);
        atomicAdd(&lcnt[NBU + (i >> BSH)], 1);
    }
    __syncthreads();
    int* mycnt = bcnt8 + (size_t)(blockIdx.x & 7) * NBUCK;
    for (int k = threadIdx.x; k < NBUCK; k += 256) {
        int v = lcnt[k];
        if (v) atomicAdd(&mycnt[k], v);
    }
}

// ---------------- single-block exclusive scan over NBUCK buckets (sums 8 copies) ----------------
__global__ void bscan_kernel(const int* __restrict__ bcnt8, int* __restrict__ bbase) {
    __shared__ int s[256];
    int t = threadIdx.x;
    int v[10];                          // 256*10 = 2560 >= NBUCK
    int tot = 0;
#pragma unroll
    for (int k = 0; k < 10; k++) {
        int idx = t * 10 + k;
        int c = 0;
        if (idx < NBUCK) {
#pragma unroll
            for (int x = 0; x < 8; x++) c += bcnt8[(size_t)x * NBUCK + idx];
        }
        v[k] = c;
        tot += c;
    }
    s[t] = tot;
    __syncthreads();
    for (int off = 1; off < 256; off <<= 1) {
        int x = (t >= off) ? s[t - off] : 0;
        __syncthreads();
        s[t] += x;
        __syncthreads();
    }
    int p = s[t] - tot;
#pragma unroll
    for (int k = 0; k < 10; k++) {
        int idx = t * 10 + k;
        if (idx < NBUCK) bbase[idx] = p;
        p += v[k];
    }
    if (t == 255) bbase[NBUCK] = TOTSLOTS;
}

// ---------------- multisplit pass 1: per-(block,bucket) counts, zero global atomics ----------------
__global__ void __launch_bounds__(256) countA_kernel(const int* __restrict__ eu,
                                                     const int* __restrict__ ei,
                                                     int* __restrict__ cntmat) {
    __shared__ int lcnt[NQ];
    for (int k = threadIdx.x; k < NQ; k += 256) lcnt[k] = 0;
    __syncthreads();
    int cls = blockIdx.x & 7;
    int sub = blockIdx.x >> 3;
    for (int t = sub * 256 + (int)threadIdx.x; t < NEDGE; t += SUBS * 256) {
        int u = eu[t];
        int i = ei[t];
        int bu = u >> BSH;
        if ((bu & 7) == cls) atomicAdd(&lcnt[bu >> 3], 1);
        int bid = NBU + (i >> BSH);
        if ((bid & 7) == cls) atomicAdd(&lcnt[bid >> 3], 1);
    }
    __syncthreads();
    int* row = cntmat + (size_t)(cls * SUBS + sub) * NQ;
    for (int k = threadIdx.x; k < NQ; k += 256) row[k] = lcnt[k];
}

// ---------------- multisplit pass 2: per-bucket scan of block counts -> basemat ----------------
__global__ void __launch_bounds__(256) bscan2_kernel(const int* __restrict__ cntmat,
                                                     const int* __restrict__ bbase,
                                                     int* __restrict__ basemat) {
    __shared__ int ws[4];
    int b = blockIdx.x;
    int cls = b & 7, q = b >> 3;
    int t = threadIdx.x;
    size_t idx = (size_t)(cls * SUBS + t) * NQ + q;
    int c = cntmat[idx];
    int inc = c;
#pragma unroll
    for (int o = 1; o < 64; o <<= 1) {
        int x = __shfl_up(inc, o);
        if ((t & 63) >= o) inc += x;
    }
    if ((t & 63) == 63) ws[t >> 6] = inc;
    __syncthreads();
    int carry = 0;
#pragma unroll
    for (int w = 0; w < 4; w++) {
        if ((t >> 6) > w) carry += ws[w];
    }
    basemat[idx] = bbase[b] + carry + inc - c;   // exclusive
}

// ---------------- multisplit pass 3: LDS-buffered rank-scatter + coalesced flush ----------------
__global__ void __launch_bounds__(256) scatterB_kernel(const int* __restrict__ eu,
                                                       const int* __restrict__ ei,
                                                       const float* __restrict__ vui,
                                                       const float* __restrict__ viu,
                                                       const int* __restrict__ cntmat,
                                                       const int* __restrict__ basemat,
                                                       int2* __restrict__ staging) {
    __shared__ int lofs[NQ + 1];
    __shared__ int lbase[NQ];
    __shared__ int lrank[NQ];
    __shared__ int2 lbuf[BUFSZ];     // 32 KB
    int cls = blockIdx.x & 7;
    int sub = blockIdx.x >> 3;
    const int* crow = cntmat + (size_t)(cls * SUBS + sub) * NQ;
    const int* brow = basemat + (size_t)(cls * SUBS + sub) * NQ;
    for (int k = threadIdx.x; k < NQ; k += 256) {
        lbase[k] = brow[k];
        lrank[k] = 0;
        lofs[k + 1] = crow[k];
    }
    if (threadIdx.x == 0) lofs[0] = 0;
    __syncthreads();
    if (threadIdx.x < 64) {
        int carry = 0;
        for (int c = 0; c < 5; c++) {
            int idx = c * 64 + (int)threadIdx.x + 1;
            int v = (idx <= NQ) ? lofs[idx] : 0;
            int inc = v;
#pragma unroll
            for (int o = 1; o < 64; o <<= 1) {
                int x = __shfl_up(inc, o);
                if ((int)threadIdx.x >= o) inc += x;
            }
            if (idx <= NQ) lofs[idx] = carry + inc;
            carry += __shfl(inc, 63);
        }
    }
    __syncthreads();
    int total = lofs[NQ];
    for (int t = sub * 256 + (int)threadIdx.x; t < NEDGE; t += SUBS * 256) {
        int u = eu[t];
        int i = ei[t];
        int bu = u >> BSH;
        if ((bu & 7) == cls) {
            int q = bu >> 3;
            int r = atomicAdd(&lrank[q], 1);
            int2 pay = make_int2(((u & 63) << 17) | i, __float_as_int(vui[t]));
            int pos = lofs[q] + r;
            if (pos < BUFSZ) lbuf[pos] = pay;
            else staging[lbase[q] + r] = pay;
        }
        int bid = NBU + (i >> BSH);
        if ((bid & 7) == cls) {
            int q = bid >> 3;
            int r = atomicAdd(&lrank[q], 1);
            int2 pay = make_int2(((i & 63) << 17) | u, __float_as_int(viu[t]));
            int pos = lofs[q] + r;
            if (pos < BUFSZ) lbuf[pos] = pay;
            else staging[lbase[q] + r] = pay;
        }
    }
    __syncthreads();
    int fl = min(total, BUFSZ);
    for (int t = threadIdx.x; t < fl; t += 256) {
        int lo = 0, hi = NQ;
        while (hi - lo > 1) {
            int mid = (lo + hi) >> 1;
            if (lofs[mid] <= t) lo = mid; else hi = mid;
        }
        staging[lbase[lo] + (t - lofs[lo])] = lbuf[t];
    }
}

// ---------------- phase B: row counts -> rowptr -> row-ordered PACKED csr ----------------
// csr entry = (src:17 << 15) | (bf16(val) low 15 bits). Edge vals are positive
// (sign bit 0), so bf16's 15 low bits encode them exactly at bf16 precision.
__global__ void __launch_bounds__(256) rsort_kernel(const int* __restrict__ bbase,
                                                    const int2* __restrict__ staging,
                                                    unsigned int* __restrict__ csr4,
                                                    int* __restrict__ rowptr) {
    __shared__ int fillr[64];
    __shared__ int rp[64];
    int b = blockIdx.x;
    int gRowBase, rows;
    if (b < NBU) {
        gRowBase = b << BSH;
        rows = min(64, U_NUM - gRowBase);
    } else {
        int rb = (b - NBU) << BSH;
        gRowBase = U_NUM + rb;
        rows = min(64, I_NUM - rb);
    }
    if (threadIdx.x < 64) fillr[threadIdx.x] = 0;
    __syncthreads();
    int beg = bbase[b], end = bbase[b + 1];
    for (int e = beg + (int)threadIdx.x; e < end; e += 256) {
        int off = staging[e].x >> 17;
        atomicAdd(&fillr[off], 1);
    }
    __syncthreads();
    if (threadIdx.x < 64) {
        int c = fillr[threadIdx.x];
        int inc = c;
#pragma unroll
        for (int o = 1; o < 64; o <<= 1) {
            int x = __shfl_up(inc, o);
            if ((int)threadIdx.x >= o) inc += x;
        }
        int excl = beg + inc - c;
        rp[threadIdx.x] = excl;
        if ((int)threadIdx.x < rows) rowptr[gRowBase + threadIdx.x] = excl;
        fillr[threadIdx.x] = 0;
    }
    if (b == 0 && threadIdx.x == 64) rowptr[NROWS] = TOTSLOTS;
    __syncthreads();
    for (int e = beg + (int)threadIdx.x; e < end; e += 256) {
        int2 pk = staging[e];
        int off = pk.x >> 17;
        int dst = rp[off] + atomicAdd(&fillr[off], 1);
        unsigned int src = (unsigned int)(pk.x & 0x1FFFF);
        unsigned int bv = f2b(__int_as_float(pk.y)) & 0x7FFFu;
        csr4[dst] = (src << 15) | bv;
    }
}

// ---------------- propagation: wave per row, 4B csr (nt stream), 32-bit gather addressing ----------------
// One dispatch per side (user rows / item rows) so the gather working set is one
// table (6.4 or 12.8 MB) instead of both (19.2 MB) -> better per-XCD L2 hit.
__global__ void __launch_bounds__(256) agg_kernel(
        const unsigned short* __restrict__ uprev, const unsigned short* __restrict__ iprev,
        unsigned short* __restrict__ unext, unsigned short* __restrict__ inext,
        const float* __restrict__ di, const float* __restrict__ dj,
        const int* __restrict__ rowptr, const unsigned int* __restrict__ csr4,
        int rowBeg, int rowCnt) {
    int w = (blockIdx.x * 256 + threadIdx.x) >> 6;
    int lane = threadIdx.x & 63;
    if (w >= rowCnt) return;
    int wid = rowBeg + w;
    const unsigned short* selfT;
    const unsigned short* srcT;
    unsigned short* dstT;
    float dscale;
    unsigned int r32;
    if (wid < U_NUM) {
        r32 = (unsigned int)wid;
        selfT = uprev; srcT = iprev; dstT = unext;
        dscale = di[wid];
    } else {
        r32 = (unsigned int)(wid - U_NUM);
        selfT = iprev; srcT = uprev; dstT = inext;
        dscale = dj[wid - U_NUM];
    }
    int beg = rowptr[wid], end = rowptr[wid + 1];
    unsigned int selfIdx = (r32 << 6) | (unsigned int)lane;
    float acc = b2f(selfT[selfIdx]) * dscale;
    int e = beg;
    for (; e + 8 <= end; e += 8) {
        unsigned int pk[8];
        float g[8];
#pragma unroll
        for (int k = 0; k < 8; k++) pk[k] = __builtin_nontemporal_load(&csr4[e + k]);
#pragma unroll
        for (int k = 0; k < 8; k++)
            g[k] = b2f(srcT[((pk[k] >> 15) << 6) | (unsigned int)lane]);
#pragma unroll
        for (int k = 0; k < 8; k++)
            acc = fmaf(b2f((unsigned short)(pk[k] & 0x7FFFu)), g[k], acc);
    }
    for (; e < end; ++e) {
        unsigned int pk = __builtin_nontemporal_load(&csr4[e]);
        float g = b2f(srcT[((pk >> 15) << 6) | (unsigned int)lane]);
        acc = fmaf(b2f((unsigned short)(pk & 0x7FFFu)), g, acc);
    }
    dstT[selfIdx] = f2b(acc);
}

// ---------------- BPR head ----------------
__global__ void __launch_bounds__(256) batch_kernel(
        const float* __restrict__ u0f, const float* __restrict__ i0f,
        const unsigned short* __restrict__ u1, const unsigned short* __restrict__ u2,
        const unsigned short* __restrict__ u3,
        const unsigned short* __restrict__ i1, const unsigned short* __restrict__ i2,
        const unsigned short* __restrict__ i3,
        const int* __restrict__ user, const int* __restrict__ ita, const int* __restrict__ itb,
        float* __restrict__ out, float* __restrict__ ls, float* __restrict__ l2a) {
    int wid = (blockIdx.x * 256 + threadIdx.x) >> 6;
    int lane = threadIdx.x & 63;
    if (wid >= BATCH) return;
    size_t uo = (size_t)user[wid] * FCT + lane;
    size_t ao = (size_t)ita[wid] * FCT + lane;
    size_t bo = (size_t)itb[wid] * FCT + lane;

    float pi, pj, l2;
    {
        float ue = u0f[uo], ie = i0f[ao], je = i0f[bo];
        pi = ue * ie; pj = ue * je; l2 = ue * ue + ie * ie + je * je;
    }
    const unsigned short* Ut[3] = {u1, u2, u3};
    const unsigned short* It[3] = {i1, i2, i3};
#pragma unroll
    for (int l = 0; l < 3; l++) {
        float ue = b2f(Ut[l][uo]), ie = b2f(It[l][ao]), je = b2f(It[l][bo]);
        pi += ue * ie;
        pj += ue * je;
        l2 += ue * ue + ie * ie + je * je;
    }
#pragma unroll
    for (int off = 32; off; off >>= 1) {
        pi += __shfl_xor(pi, off);
        pj += __shfl_xor(pj, off);
        l2 += __shfl_xor(l2, off);
    }
    if (lane == 0) {
        out[wid] = pi;
        out[BATCH + wid] = pj;
        float x = pi - pj;
        ls[wid] = fminf(x, 0.0f) - log1pf(expf(-fabsf(x)));
        l2a[wid] = 0.01f * l2;
    }
}

__global__ void final_kernel(const float* __restrict__ ls, const float* __restrict__ l2a,
                             float* __restrict__ out) {
    __shared__ float s1[256], s2[256];
    int t = threadIdx.x;
    float a = 0.f, b = 0.f;
    for (int i = t; i < BATCH; i += 256) {
        a += ls[i];
        b += l2a[i];
    }
    s1[t] = a;
    s2[t] = b;
    __syncthreads();
    for (int off = 128; off; off >>= 1) {
        if (t < off) {
            s1[t] += s1[t + off];
            s2[t] += s2[t + off];
        }
        __syncthreads();
    }
    if (t == 0) {
        float loss2 = -s1[0] / (float)BATCH;
        float l2m = s2[0] / (float)BATCH;
        out[2 * BATCH] = loss2 + l2m;
        out[2 * BATCH + 1] = loss2;
    }
}

// ---------------- launch ----------------
extern "C" void kernel_launch(void* const* d_in, const int* in_sizes, int n_in,
                              void* d_out, int out_size, void* d_ws, size_t ws_size,
                              hipStream_t stream) {
    const float* u0f = (const float*)d_in[0];
    const float* i0f = (const float*)d_in[1];
    const float* di  = (const float*)d_in[2];
    const float* dj  = (const float*)d_in[3];
    const float* vui = (const float*)d_in[4];
    const float* viu = (const float*)d_in[5];
    const int*   eu  = (const int*)d_in[6];
    const int*   ei  = (const int*)d_in[7];
    const int*   usr = (const int*)d_in[8];
    const int*   ita = (const int*)d_in[9];
    const int*   itb = (const int*)d_in[10];
    float* out = (float*)d_out;

    char* p = (char*)d_ws;
    auto alloc = [&](size_t bytes) -> char* {
        char* r = p;
        p += (bytes + 255) & ~(size_t)255;
        return r;
    };
    unsigned short* u0b = (unsigned short*)alloc((size_t)U_NUM * FCT * 2);
    unsigned short* u1b = (unsigned short*)alloc((size_t)U_NUM * FCT * 2);
    unsigned short* i0b = (unsigned short*)alloc((size_t)I_NUM * FCT * 2);
    unsigned short* i1b = (unsigned short*)alloc((size_t)I_NUM * FCT * 2);
    unsigned int* csr4 = (unsigned int*)alloc((size_t)TOTSLOTS * 4);   // 25.6 MB
    int2* staging = (int2*)alloc((size_t)TOTSLOTS * 8);                // 51.2 MB
    int* rowptr  = (int*)alloc((size_t)(NROWS + 1) * 4);
    int* bcnt8   = (int*)alloc((size_t)8 * NBUCK * 4);
    int* bbase   = (int*)alloc((size_t)(NBUCK + 1) * 4);
    int* cntmat  = (int*)alloc((size_t)8 * SUBS * NQ * 4);
    int* basemat = (int*)alloc((size_t)8 * SUBS * NQ * 4);
    float* ls    = (float*)alloc((size_t)BATCH * 4);
    float* l2a   = (float*)alloc((size_t)BATCH * 4);
    // overlay levels 2,3 on staging (dead after rsort; written by later agg launches)
    unsigned short* u2b = (unsigned short*)staging;
    unsigned short* u3b = u2b + (size_t)U_NUM * FCT;
    unsigned short* i2b = u3b + (size_t)U_NUM * FCT;
    unsigned short* i3b = i2b + (size_t)I_NUM * FCT;

    hipMemsetAsync(bcnt8, 0, (size_t)8 * NBUCK * 4, stream);

    conv_kernel<<<(U_NUM * FCT / 4 + 255) / 256, 256, 0, stream>>>(u0f, u0b, U_NUM * FCT / 4);
    conv_kernel<<<(I_NUM * FCT / 4 + 255) / 256, 256, 0, stream>>>(i0f, i0b, I_NUM * FCT / 4);

    bhist_kernel<<<512, 256, 0, stream>>>(eu, ei, bcnt8);
    bscan_kernel<<<1, 256, 0, stream>>>(bcnt8, bbase);

    countA_kernel<<<2048, 256, 0, stream>>>(eu, ei, cntmat);
    bscan2_kernel<<<NBUCK, 256, 0, stream>>>(cntmat, bbase, basemat);
    scatterB_kernel<<<2048, 256, 0, stream>>>(eu, ei, vui, viu, cntmat, basemat, staging);
    rsort_kernel<<<NBUCK, 256, 0, stream>>>(bbase, staging, csr4, rowptr);

    int gU = (U_NUM * 64 + 255) / 256;   // user-row waves
    int gI = (I_NUM * 64 + 255) / 256;   // item-row waves
    agg_kernel<<<gU, 256, 0, stream>>>(u0b, i0b, u1b, i1b, di, dj, rowptr, csr4, 0, U_NUM);
    agg_kernel<<<gI, 256, 0, stream>>>(u0b, i0b, u1b, i1b, di, dj, rowptr, csr4, U_NUM, I_NUM);
    agg_kernel<<<gU, 256, 0, stream>>>(u1b, i1b, u2b, i2b, di, dj, rowptr, csr4, 0, U_NUM);
    agg_kernel<<<gI, 256, 0, stream>>>(u1b, i1b, u2b, i2b, di, dj, rowptr, csr4, U_NUM, I_NUM);
    agg_kernel<<<gU, 256, 0, stream>>>(u2b, i2b, u3b, i3b, di, dj, rowptr, csr4, 0, U_NUM);
    agg_kernel<<<gI, 256, 0, stream>>>(u2b, i2b, u3b, i3b, di, dj, rowptr, csr4, U_NUM, I_NUM);

    batch_kernel<<<(BATCH * 64) / 256, 256, 0, stream>>>(u0f, i0f, u1b, u2b, u3b,
                                                         i1b, i2b, i3b,
                                                         usr, ita, itb, out, ls, l2a);
    final_kernel<<<1, 256, 0, stream>>>(ls, l2a, out);
}

// Round 13
// 710.254 us; speedup vs baseline: 1.1970x; 1.1970x over previous
//
#include <hip/hip_runtime.h>

#define U_NUM   100000
#define I_NUM   50000
#define FCT     64
#define NEDGE   3200000
#define BATCH   16384
#define NROWS   (U_NUM + I_NUM)      // 150000
#define TOTSLOTS (2 * NEDGE)         // 6400000

#define BSH 6                        // 64 rows per bucket
#define NBU 1563                     // ceil(100000/64)
#define NBI 782                      // ceil(50000/64)
#define NBUCK (NBU + NBI)            // 2345
#define NQ   294                     // ceil(NBUCK/8) buckets per class
#define SUBS 256                     // blocks per class in scatter grid
#define BUFSZ 4096                   // LDS payload buffer (expected fill 3125)

__device__ __forceinline__ unsigned short f2b(float f) {
    unsigned int x = __float_as_uint(f);
    unsigned int r = (x + 0x7FFFu + ((x >> 16) & 1u)) >> 16;   // RNE
    return (unsigned short)r;
}
__device__ __forceinline__ float b2f(unsigned short u) {
    return __uint_as_float(((unsigned int)u) << 16);
}

// ---------------- fp32 -> bf16 table conversion ----------------
__global__ void conv_kernel(const float* __restrict__ in, unsigned short* __restrict__ out, int n4) {
    int t = blockIdx.x * blockDim.x + threadIdx.x;
    if (t >= n4) return;
    float4 v = *reinterpret_cast<const float4*>(in + (size_t)t * 4);
    ushort4 o;
    o.x = f2b(v.x); o.y = f2b(v.y); o.z = f2b(v.z); o.w = f2b(v.w);
    *reinterpret_cast<ushort4*>(out + (size_t)t * 4) = o;
}

// ---------------- bucket histogram: LDS-private count, flush to class copy ----------------
__global__ void __launch_bounds__(256) bhist_kernel(const int* __restrict__ eu,
                                                    const int* __restrict__ ei,
                                                    int* __restrict__ bcnt8) {
    __shared__ int lcnt[NBUCK];
    for (int k = threadIdx.x; k < NBUCK; k += 256) lcnt[k] = 0;
    __syncthreads();
    int stride = gridDim.x * 256;
    for (int t = blockIdx.x * 256 + (int)threadIdx.x; t < NEDGE; t += stride) {
        int u = eu[t];
        int i = ei[t];
        atomicAdd(&lcnt[u >> BSH], 1);
        atomicAdd(&lcnt[NBU + (i >> BSH)], 1);
    }
    __syncthreads();
    int* mycnt = bcnt8 + (size_t)(blockIdx.x & 7) * NBUCK;
    for (int k = threadIdx.x; k < NBUCK; k += 256) {
        int v = lcnt[k];
        if (v) atomicAdd(&mycnt[k], v);
    }
}

// ---------------- single-block exclusive scan over NBUCK buckets (sums 8 copies) ----------------
__global__ void bscan_kernel(const int* __restrict__ bcnt8, int* __restrict__ bbase) {
    __shared__ int s[256];
    int t = threadIdx.x;
    int v[10];                          // 256*10 = 2560 >= NBUCK
    int tot = 0;
#pragma unroll
    for (int k = 0; k < 10; k++) {
        int idx = t * 10 + k;
        int c = 0;
        if (idx < NBUCK) {
#pragma unroll
            for (int x = 0; x < 8; x++) c += bcnt8[(size_t)x * NBUCK + idx];
        }
        v[k] = c;
        tot += c;
    }
    s[t] = tot;
    __syncthreads();
    for (int off = 1; off < 256; off <<= 1) {
        int x = (t >= off) ? s[t - off] : 0;
        __syncthreads();
        s[t] += x;
        __syncthreads();
    }
    int p = s[t] - tot;
#pragma unroll
    for (int k = 0; k < 10; k++) {
        int idx = t * 10 + k;
        if (idx < NBUCK) bbase[idx] = p;
        p += v[k];
    }
    if (t == 255) bbase[NBUCK] = TOTSLOTS;
}

// ---------------- multisplit pass 1: per-(block,bucket) counts, zero global atomics ----------------
__global__ void __launch_bounds__(256) countA_kernel(const int* __restrict__ eu,
                                                     const int* __restrict__ ei,
                                                     int* __restrict__ cntmat) {
    __shared__ int lcnt[NQ];
    for (int k = threadIdx.x; k < NQ; k += 256) lcnt[k] = 0;
    __syncthreads();
    int cls = blockIdx.x & 7;
    int sub = blockIdx.x >> 3;
    for (int t = sub * 256 + (int)threadIdx.x; t < NEDGE; t += SUBS * 256) {
        int u = eu[t];
        int i = ei[t];
        int bu = u >> BSH;
        if ((bu & 7) == cls) atomicAdd(&lcnt[bu >> 3], 1);
        int bid = NBU + (i >> BSH);
        if ((bid & 7) == cls) atomicAdd(&lcnt[bid >> 3], 1);
    }
    __syncthreads();
    int* row = cntmat + (size_t)(cls * SUBS + sub) * NQ;
    for (int k = threadIdx.x; k < NQ; k += 256) row[k] = lcnt[k];
}

// ---------------- multisplit pass 2: per-bucket scan of block counts -> basemat ----------------
__global__ void __launch_bounds__(256) bscan2_kernel(const int* __restrict__ cntmat,
                                                     const int* __restrict__ bbase,
                                                     int* __restrict__ basemat) {
    __shared__ int ws[4];
    int b = blockIdx.x;
    int cls = b & 7, q = b >> 3;
    int t = threadIdx.x;
    size_t idx = (size_t)(cls * SUBS + t) * NQ + q;
    int c = cntmat[idx];
    int inc = c;
#pragma unroll
    for (int o = 1; o < 64; o <<= 1) {
        int x = __shfl_up(inc, o);
        if ((t & 63) >= o) inc += x;
    }
    if ((t & 63) == 63) ws[t >> 6] = inc;
    __syncthreads();
    int carry = 0;
#pragma unroll
    for (int w = 0; w < 4; w++) {
        if ((t >> 6) > w) carry += ws[w];
    }
    basemat[idx] = bbase[b] + carry + inc - c;   // exclusive
}

// ---------------- multisplit pass 3: LDS-buffered rank-scatter + coalesced flush ----------------
__global__ void __launch_bounds__(256) scatterB_kernel(const int* __restrict__ eu,
                                                       const int* __restrict__ ei,
                                                       const float* __restrict__ vui,
                                                       const float* __restrict__ viu,
                                                       const int* __restrict__ cntmat,
                                                       const int* __restrict__ basemat,
                                                       int2* __restrict__ staging) {
    __shared__ int lofs[NQ + 1];
    __shared__ int lbase[NQ];
    __shared__ int lrank[NQ];
    __shared__ int2 lbuf[BUFSZ];     // 32 KB
    int cls = blockIdx.x & 7;
    int sub = blockIdx.x >> 3;
    const int* crow = cntmat + (size_t)(cls * SUBS + sub) * NQ;
    const int* brow = basemat + (size_t)(cls * SUBS + sub) * NQ;
    for (int k = threadIdx.x; k < NQ; k += 256) {
        lbase[k] = brow[k];
        lrank[k] = 0;
        lofs[k + 1] = crow[k];
    }
    if (threadIdx.x == 0) lofs[0] = 0;
    __syncthreads();
    if (threadIdx.x < 64) {
        int carry = 0;
        for (int c = 0; c < 5; c++) {
            int idx = c * 64 + (int)threadIdx.x + 1;
            int v = (idx <= NQ) ? lofs[idx] : 0;
            int inc = v;
#pragma unroll
            for (int o = 1; o < 64; o <<= 1) {
                int x = __shfl_up(inc, o);
                if ((int)threadIdx.x >= o) inc += x;
            }
            if (idx <= NQ) lofs[idx] = carry + inc;
            carry += __shfl(inc, 63);
        }
    }
    __syncthreads();
    int total = lofs[NQ];
    for (int t = sub * 256 + (int)threadIdx.x; t < NEDGE; t += SUBS * 256) {
        int u = eu[t];
        int i = ei[t];
        int bu = u >> BSH;
        if ((bu & 7) == cls) {
            int q = bu >> 3;
            int r = atomicAdd(&lrank[q], 1);
            int2 pay = make_int2(((u & 63) << 17) | i, __float_as_int(vui[t]));
            int pos = lofs[q] + r;
            if (pos < BUFSZ) lbuf[pos] = pay;
            else staging[lbase[q] + r] = pay;
        }
        int bid = NBU + (i >> BSH);
        if ((bid & 7) == cls) {
            int q = bid >> 3;
            int r = atomicAdd(&lrank[q], 1);
            int2 pay = make_int2(((i & 63) << 17) | u, __float_as_int(viu[t]));
            int pos = lofs[q] + r;
            if (pos < BUFSZ) lbuf[pos] = pay;
            else staging[lbase[q] + r] = pay;
        }
    }
    __syncthreads();
    int fl = min(total, BUFSZ);
    for (int t = threadIdx.x; t < fl; t += 256) {
        int lo = 0, hi = NQ;
        while (hi - lo > 1) {
            int mid = (lo + hi) >> 1;
            if (lofs[mid] <= t) lo = mid; else hi = mid;
        }
        staging[lbase[lo] + (t - lofs[lo])] = lbuf[t];
    }
}

// ---------------- phase B: row counts -> rowptr -> row-ordered PACKED csr ----------------
// csr entry = (src:17 << 15) | (bf16(val) low 15 bits); vals positive so lossless-of-bf16.
__global__ void __launch_bounds__(256) rsort_kernel(const int* __restrict__ bbase,
                                                    const int2* __restrict__ staging,
                                                    unsigned int* __restrict__ csr4,
                                                    int* __restrict__ rowptr) {
    __shared__ int fillr[64];
    __shared__ int rp[64];
    int b = blockIdx.x;
    int gRowBase, rows;
    if (b < NBU) {
        gRowBase = b << BSH;
        rows = min(64, U_NUM - gRowBase);
    } else {
        int rb = (b - NBU) << BSH;
        gRowBase = U_NUM + rb;
        rows = min(64, I_NUM - rb);
    }
    if (threadIdx.x < 64) fillr[threadIdx.x] = 0;
    __syncthreads();
    int beg = bbase[b], end = bbase[b + 1];
    for (int e = beg + (int)threadIdx.x; e < end; e += 256) {
        int off = staging[e].x >> 17;
        atomicAdd(&fillr[off], 1);
    }
    __syncthreads();
    if (threadIdx.x < 64) {
        int c = fillr[threadIdx.x];
        int inc = c;
#pragma unroll
        for (int o = 1; o < 64; o <<= 1) {
            int x = __shfl_up(inc, o);
            if ((int)threadIdx.x >= o) inc += x;
        }
        int excl = beg + inc - c;
        rp[threadIdx.x] = excl;
        if ((int)threadIdx.x < rows) rowptr[gRowBase + threadIdx.x] = excl;
        fillr[threadIdx.x] = 0;
    }
    if (b == 0 && threadIdx.x == 64) rowptr[NROWS] = TOTSLOTS;
    __syncthreads();
    for (int e = beg + (int)threadIdx.x; e < end; e += 256) {
        int2 pk = staging[e];
        int off = pk.x >> 17;
        int dst = rp[off] + atomicAdd(&fillr[off], 1);
        unsigned int src = (unsigned int)(pk.x & 0x1FFFF);
        unsigned int bv = f2b(__int_as_float(pk.y)) & 0x7FFFu;
        csr4[dst] = (src << 15) | bv;
    }
}

// ---------------- propagation: wave per row, 4B csr (CACHED loads), combined dispatch ----------------
__global__ void __launch_bounds__(256) agg_kernel(
        const unsigned short* __restrict__ uprev, const unsigned short* __restrict__ iprev,
        unsigned short* __restrict__ unext, unsigned short* __restrict__ inext,
        const float* __restrict__ di, const float* __restrict__ dj,
        const int* __restrict__ rowptr, const unsigned int* __restrict__ csr4) {
    int wid = (blockIdx.x * 256 + threadIdx.x) >> 6;
    int lane = threadIdx.x & 63;
    if (wid >= NROWS) return;
    const unsigned short* selfT;
    const unsigned short* srcT;
    unsigned short* dstT;
    float dscale;
    unsigned int r32;
    if (wid < U_NUM) {
        r32 = (unsigned int)wid;
        selfT = uprev; srcT = iprev; dstT = unext;
        dscale = di[wid];
    } else {
        r32 = (unsigned int)(wid - U_NUM);
        selfT = iprev; srcT = uprev; dstT = inext;
        dscale = dj[wid - U_NUM];
    }
    int beg = rowptr[wid], end = rowptr[wid + 1];
    unsigned int selfIdx = (r32 << 6) | (unsigned int)lane;
    float acc = b2f(selfT[selfIdx]) * dscale;
    int e = beg;
    for (; e + 8 <= end; e += 8) {
        unsigned int pk[8];
        float g[8];
#pragma unroll
        for (int k = 0; k < 8; k++) pk[k] = csr4[e + k];
#pragma unroll
        for (int k = 0; k < 8; k++)
            g[k] = b2f(srcT[((pk[k] >> 15) << 6) | (unsigned int)lane]);
#pragma unroll
        for (int k = 0; k < 8; k++)
            acc = fmaf(b2f((unsigned short)(pk[k] & 0x7FFFu)), g[k], acc);
    }
    for (; e < end; ++e) {
        unsigned int pk = csr4[e];
        float g = b2f(srcT[((pk >> 15) << 6) | (unsigned int)lane]);
        acc = fmaf(b2f((unsigned short)(pk & 0x7FFFu)), g, acc);
    }
    dstT[selfIdx] = f2b(acc);
}

// ---------------- BPR head ----------------
__global__ void __launch_bounds__(256) batch_kernel(
        const float* __restrict__ u0f, const float* __restrict__ i0f,
        const unsigned short* __restrict__ u1, const unsigned short* __restrict__ u2,
        const unsigned short* __restrict__ u3,
        const unsigned short* __restrict__ i1, const unsigned short* __restrict__ i2,
        const unsigned short* __restrict__ i3,
        const int* __restrict__ user, const int* __restrict__ ita, const int* __restrict__ itb,
        float* __restrict__ out, float* __restrict__ ls, float* __restrict__ l2a) {
    int wid = (blockIdx.x * 256 + threadIdx.x) >> 6;
    int lane = threadIdx.x & 63;
    if (wid >= BATCH) return;
    size_t uo = (size_t)user[wid] * FCT + lane;
    size_t ao = (size_t)ita[wid] * FCT + lane;
    size_t bo = (size_t)itb[wid] * FCT + lane;

    float pi, pj, l2;
    {
        float ue = u0f[uo], ie = i0f[ao], je = i0f[bo];
        pi = ue * ie; pj = ue * je; l2 = ue * ue + ie * ie + je * je;
    }
    const unsigned short* Ut[3] = {u1, u2, u3};
    const unsigned short* It[3] = {i1, i2, i3};
#pragma unroll
    for (int l = 0; l < 3; l++) {
        float ue = b2f(Ut[l][uo]), ie = b2f(It[l][ao]), je = b2f(It[l][bo]);
        pi += ue * ie;
        pj += ue * je;
        l2 += ue * ue + ie * ie + je * je;
    }
#pragma unroll
    for (int off = 32; off; off >>= 1) {
        pi += __shfl_xor(pi, off);
        pj += __shfl_xor(pj, off);
        l2 += __shfl_xor(l2, off);
    }
    if (lane == 0) {
        out[wid] = pi;
        out[BATCH + wid] = pj;
        float x = pi - pj;
        ls[wid] = fminf(x, 0.0f) - log1pf(expf(-fabsf(x)));
        l2a[wid] = 0.01f * l2;
    }
}

__global__ void final_kernel(const float* __restrict__ ls, const float* __restrict__ l2a,
                             float* __restrict__ out) {
    __shared__ float s1[256], s2[256];
    int t = threadIdx.x;
    float a = 0.f, b = 0.f;
    for (int i = t; i < BATCH; i += 256) {
        a += ls[i];
        b += l2a[i];
    }
    s1[t] = a;
    s2[t] = b;
    __syncthreads();
    for (int off = 128; off; off >>= 1) {
        if (t < off) {
            s1[t] += s1[t + off];
            s2[t] += s2[t + off];
        }
        __syncthreads();
    }
    if (t == 0) {
        float loss2 = -s1[0] / (float)BATCH;
        float l2m = s2[0] / (float)BATCH;
        out[2 * BATCH] = loss2 + l2m;
        out[2 * BATCH + 1] = loss2;
    }
}

// ---------------- launch ----------------
extern "C" void kernel_launch(void* const* d_in, const int* in_sizes, int n_in,
                              void* d_out, int out_size, void* d_ws, size_t ws_size,
                              hipStream_t stream) {
    const float* u0f = (const float*)d_in[0];
    const float* i0f = (const float*)d_in[1];
    const float* di  = (const float*)d_in[2];
    const float* dj  = (const float*)d_in[3];
    const float* vui = (const float*)d_in[4];
    const float* viu = (const float*)d_in[5];
    const int*   eu  = (const int*)d_in[6];
    const int*   ei  = (const int*)d_in[7];
    const int*   usr = (const int*)d_in[8];
    const int*   ita = (const int*)d_in[9];
    const int*   itb = (const int*)d_in[10];
    float* out = (float*)d_out;

    char* p = (char*)d_ws;
    auto alloc = [&](size_t bytes) -> char* {
        char* r = p;
        p += (bytes + 255) & ~(size_t)255;
        return r;
    };
    unsigned short* u0b = (unsigned short*)alloc((size_t)U_NUM * FCT * 2);
    unsigned short* u1b = (unsigned short*)alloc((size_t)U_NUM * FCT * 2);
    unsigned short* i0b = (unsigned short*)alloc((size_t)I_NUM * FCT * 2);
    unsigned short* i1b = (unsigned short*)alloc((size_t)I_NUM * FCT * 2);
    unsigned int* csr4 = (unsigned int*)alloc((size_t)TOTSLOTS * 4);   // 25.6 MB
    int2* staging = (int2*)alloc((size_t)TOTSLOTS * 8);                // 51.2 MB
    int* rowptr  = (int*)alloc((size_t)(NROWS + 1) * 4);
    int* bcnt8   = (int*)alloc((size_t)8 * NBUCK * 4);
    int* bbase   = (int*)alloc((size_t)(NBUCK + 1) * 4);
    int* cntmat  = (int*)alloc((size_t)8 * SUBS * NQ * 4);
    int* basemat = (int*)alloc((size_t)8 * SUBS * NQ * 4);
    float* ls    = (float*)alloc((size_t)BATCH * 4);
    float* l2a   = (float*)alloc((size_t)BATCH * 4);
    // overlay levels 2,3 on staging (dead after rsort; written by later agg launches)
    unsigned short* u2b = (unsigned short*)staging;
    unsigned short* u3b = u2b + (size_t)U_NUM * FCT;
    unsigned short* i2b = u3b + (size_t)U_NUM * FCT;
    unsigned short* i3b = i2b + (size_t)I_NUM * FCT;

    hipMemsetAsync(bcnt8, 0, (size_t)8 * NBUCK * 4, stream);

    conv_kernel<<<(U_NUM * FCT / 4 + 255) / 256, 256, 0, stream>>>(u0f, u0b, U_NUM * FCT / 4);
    conv_kernel<<<(I_NUM * FCT / 4 + 255) / 256, 256, 0, stream>>>(i0f, i0b, I_NUM * FCT / 4);

    bhist_kernel<<<512, 256, 0, stream>>>(eu, ei, bcnt8);
    bscan_kernel<<<1, 256, 0, stream>>>(bcnt8, bbase);

    countA_kernel<<<2048, 256, 0, stream>>>(eu, ei, cntmat);
    bscan2_kernel<<<NBUCK, 256, 0, stream>>>(cntmat, bbase, basemat);
    scatterB_kernel<<<2048, 256, 0, stream>>>(eu, ei, vui, viu, cntmat, basemat, staging);
    rsort_kernel<<<NBUCK, 256, 0, stream>>>(bbase, staging, csr4, rowptr);

    int aggGrid = (NROWS * 64) / 256 + 1;
    agg_kernel<<<aggGrid, 256, 0, stream>>>(u0b, i0b, u1b, i1b, di, dj, rowptr, csr4);
    agg_kernel<<<aggGrid, 256, 0, stream>>>(u1b, i1b, u2b, i2b, di, dj, rowptr, csr4);
    agg_kernel<<<aggGrid, 256, 0, stream>>>(u2b, i2b, u3b, i3b, di, dj, rowptr, csr4);

    batch_kernel<<<(BATCH * 64) / 256, 256, 0, stream>>>(u0f, i0f, u1b, u2b, u3b,
                                                         i1b, i2b, i3b,
                                                         usr, ita, itb, out, ls, l2a);
    final_kernel<<<1, 256, 0, stream>>>(ls, l2a, out);
}

// Round 14
// 633.602 us; speedup vs baseline: 1.3418x; 1.1210x over previous
//
#include <hip/hip_runtime.h>

#define U_NUM   100000
#define I_NUM   50000
#define FCT     64
#define NEDGE   3200000
#define BATCH   16384
#define NROWS   (U_NUM + I_NUM)      // 150000
#define TOTSLOTS (2 * NEDGE)         // 6400000

#define BSH 6                        // 64 rows per bucket
#define NBU 1563                     // ceil(100000/64)
#define NBI 782                      // ceil(50000/64)
#define NBUCK (NBU + NBI)            // 2345
#define NQ   294                     // ceil(NBUCK/8) buckets per class
#define SUBS 256                     // blocks per class in scatter grid
#define BUFSZ 4096                   // LDS payload buffer (expected fill 3125)

__device__ __forceinline__ unsigned short f2b(float f) {
    unsigned int x = __float_as_uint(f);
    unsigned int r = (x + 0x7FFFu + ((x >> 16) & 1u)) >> 16;   // RNE
    return (unsigned short)r;
}
__device__ __forceinline__ float b2f(unsigned short u) {
    return __uint_as_float(((unsigned int)u) << 16);
}

// ---------------- fp32 -> bf16 table conversion ----------------
__global__ void conv_kernel(const float* __restrict__ in, unsigned short* __restrict__ out, int n4) {
    int t = blockIdx.x * blockDim.x + threadIdx.x;
    if (t >= n4) return;
    float4 v = *reinterpret_cast<const float4*>(in + (size_t)t * 4);
    ushort4 o;
    o.x = f2b(v.x); o.y = f2b(v.y); o.z = f2b(v.z); o.w = f2b(v.w);
    *reinterpret_cast<ushort4*>(out + (size_t)t * 4) = o;
}

// ---------------- bucket histogram: LDS-private count, flush to class copy ----------------
__global__ void __launch_bounds__(256) bhist_kernel(const int* __restrict__ eu,
                                                    const int* __restrict__ ei,
                                                    int* __restrict__ bcnt8) {
    __shared__ int lcnt[NBUCK];
    for (int k = threadIdx.x; k < NBUCK; k += 256) lcnt[k] = 0;
    __syncthreads();
    int stride = gridDim.x * 256;
    for (int t = blockIdx.x * 256 + (int)threadIdx.x; t < NEDGE; t += stride) {
        int u = eu[t];
        int i = ei[t];
        atomicAdd(&lcnt[u >> BSH], 1);
        atomicAdd(&lcnt[NBU + (i >> BSH)], 1);
    }
    __syncthreads();
    int* mycnt = bcnt8 + (size_t)(blockIdx.x & 7) * NBUCK;
    for (int k = threadIdx.x; k < NBUCK; k += 256) {
        int v = lcnt[k];
        if (v) atomicAdd(&mycnt[k], v);
    }
}

// ---------------- single-block exclusive scan over NBUCK buckets (sums 8 copies) ----------------
__global__ void bscan_kernel(const int* __restrict__ bcnt8, int* __restrict__ bbase) {
    __shared__ int s[256];
    int t = threadIdx.x;
    int v[10];                          // 256*10 = 2560 >= NBUCK
    int tot = 0;
#pragma unroll
    for (int k = 0; k < 10; k++) {
        int idx = t * 10 + k;
        int c = 0;
        if (idx < NBUCK) {
#pragma unroll
            for (int x = 0; x < 8; x++) c += bcnt8[(size_t)x * NBUCK + idx];
        }
        v[k] = c;
        tot += c;
    }
    s[t] = tot;
    __syncthreads();
    for (int off = 1; off < 256; off <<= 1) {
        int x = (t >= off) ? s[t - off] : 0;
        __syncthreads();
        s[t] += x;
        __syncthreads();
    }
    int p = s[t] - tot;
#pragma unroll
    for (int k = 0; k < 10; k++) {
        int idx = t * 10 + k;
        if (idx < NBUCK) bbase[idx] = p;
        p += v[k];
    }
    if (t == 255) bbase[NBUCK] = TOTSLOTS;
}

// ---------------- multisplit pass 1: per-(block,bucket) counts, zero global atomics ----------------
__global__ void __launch_bounds__(256) countA_kernel(const int* __restrict__ eu,
                                                     const int* __restrict__ ei,
                                                     int* __restrict__ cntmat) {
    __shared__ int lcnt[NQ];
    for (int k = threadIdx.x; k < NQ; k += 256) lcnt[k] = 0;
    __syncthreads();
    int cls = blockIdx.x & 7;
    int sub = blockIdx.x >> 3;
    for (int t = sub * 256 + (int)threadIdx.x; t < NEDGE; t += SUBS * 256) {
        int u = eu[t];
        int i = ei[t];
        int bu = u >> BSH;
        if ((bu & 7) == cls) atomicAdd(&lcnt[bu >> 3], 1);
        int bid = NBU + (i >> BSH);
        if ((bid & 7) == cls) atomicAdd(&lcnt[bid >> 3], 1);
    }
    __syncthreads();
    int* row = cntmat + (size_t)(cls * SUBS + sub) * NQ;
    for (int k = threadIdx.x; k < NQ; k += 256) row[k] = lcnt[k];
}

// ---------------- multisplit pass 2: per-bucket scan of block counts -> basemat ----------------
__global__ void __launch_bounds__(256) bscan2_kernel(const int* __restrict__ cntmat,
                                                     const int* __restrict__ bbase,
                                                     int* __restrict__ basemat) {
    __shared__ int ws[4];
    int b = blockIdx.x;
    int cls = b & 7, q = b >> 3;
    int t = threadIdx.x;
    size_t idx = (size_t)(cls * SUBS + t) * NQ + q;
    int c = cntmat[idx];
    int inc = c;
#pragma unroll
    for (int o = 1; o < 64; o <<= 1) {
        int x = __shfl_up(inc, o);
        if ((t & 63) >= o) inc += x;
    }
    if ((t & 63) == 63) ws[t >> 6] = inc;
    __syncthreads();
    int carry = 0;
#pragma unroll
    for (int w = 0; w < 4; w++) {
        if ((t >> 6) > w) carry += ws[w];
    }
    basemat[idx] = bbase[b] + carry + inc - c;   // exclusive
}

// ---------------- multisplit pass 3: LDS-buffered rank-scatter + coalesced flush ----------------
__global__ void __launch_bounds__(256) scatterB_kernel(const int* __restrict__ eu,
                                                       const int* __restrict__ ei,
                                                       const float* __restrict__ vui,
                                                       const float* __restrict__ viu,
                                                       const int* __restrict__ cntmat,
                                                       const int* __restrict__ basemat,
                                                       int2* __restrict__ staging) {
    __shared__ int lofs[NQ + 1];
    __shared__ int lbase[NQ];
    __shared__ int lrank[NQ];
    __shared__ int2 lbuf[BUFSZ];     // 32 KB
    int cls = blockIdx.x & 7;
    int sub = blockIdx.x >> 3;
    const int* crow = cntmat + (size_t)(cls * SUBS + sub) * NQ;
    const int* brow = basemat + (size_t)(cls * SUBS + sub) * NQ;
    for (int k = threadIdx.x; k < NQ; k += 256) {
        lbase[k] = brow[k];
        lrank[k] = 0;
        lofs[k + 1] = crow[k];
    }
    if (threadIdx.x == 0) lofs[0] = 0;
    __syncthreads();
    if (threadIdx.x < 64) {
        int carry = 0;
        for (int c = 0; c < 5; c++) {
            int idx = c * 64 + (int)threadIdx.x + 1;
            int v = (idx <= NQ) ? lofs[idx] : 0;
            int inc = v;
#pragma unroll
            for (int o = 1; o < 64; o <<= 1) {
                int x = __shfl_up(inc, o);
                if ((int)threadIdx.x >= o) inc += x;
            }
            if (idx <= NQ) lofs[idx] = carry + inc;
            carry += __shfl(inc, 63);
        }
    }
    __syncthreads();
    int total = lofs[NQ];
    for (int t = sub * 256 + (int)threadIdx.x; t < NEDGE; t += SUBS * 256) {
        int u = eu[t];
        int i = ei[t];
        int bu = u >> BSH;
        if ((bu & 7) == cls) {
            int q = bu >> 3;
            int r = atomicAdd(&lrank[q], 1);
            int2 pay = make_int2(((u & 63) << 17) | i, __float_as_int(vui[t]));
            int pos = lofs[q] + r;
            if (pos < BUFSZ) lbuf[pos] = pay;
            else staging[lbase[q] + r] = pay;
        }
        int bid = NBU + (i >> BSH);
        if ((bid & 7) == cls) {
            int q = bid >> 3;
            int r = atomicAdd(&lrank[q], 1);
            int2 pay = make_int2(((i & 63) << 17) | u, __float_as_int(viu[t]));
            int pos = lofs[q] + r;
            if (pos < BUFSZ) lbuf[pos] = pay;
            else staging[lbase[q] + r] = pay;
        }
    }
    __syncthreads();
    int fl = min(total, BUFSZ);
    for (int t = threadIdx.x; t < fl; t += 256) {
        int lo = 0, hi = NQ;
        while (hi - lo > 1) {
            int mid = (lo + hi) >> 1;
            if (lofs[mid] <= t) lo = mid; else hi = mid;
        }
        staging[lbase[lo] + (t - lofs[lo])] = lbuf[t];
    }
}

// ---------------- phase B: row counts -> rowptr -> row-ordered PACKED csr ----------------
// csr entry = (src:17 << 15) | (bf16(val) low 15 bits); vals positive so lossless-of-bf16.
__global__ void __launch_bounds__(256) rsort_kernel(const int* __restrict__ bbase,
                                                    const int2* __restrict__ staging,
                                                    unsigned int* __restrict__ csr4,
                                                    int* __restrict__ rowptr) {
    __shared__ int fillr[64];
    __shared__ int rp[64];
    int b = blockIdx.x;
    int gRowBase, rows;
    if (b < NBU) {
        gRowBase = b << BSH;
        rows = min(64, U_NUM - gRowBase);
    } else {
        int rb = (b - NBU) << BSH;
        gRowBase = U_NUM + rb;
        rows = min(64, I_NUM - rb);
    }
    if (threadIdx.x < 64) fillr[threadIdx.x] = 0;
    __syncthreads();
    int beg = bbase[b], end = bbase[b + 1];
    for (int e = beg + (int)threadIdx.x; e < end; e += 256) {
        int off = staging[e].x >> 17;
        atomicAdd(&fillr[off], 1);
    }
    __syncthreads();
    if (threadIdx.x < 64) {
        int c = fillr[threadIdx.x];
        int inc = c;
#pragma unroll
        for (int o = 1; o < 64; o <<= 1) {
            int x = __shfl_up(inc, o);
            if ((int)threadIdx.x >= o) inc += x;
        }
        int excl = beg + inc - c;
        rp[threadIdx.x] = excl;
        if ((int)threadIdx.x < rows) rowptr[gRowBase + threadIdx.x] = excl;
        fillr[threadIdx.x] = 0;
    }
    if (b == 0 && threadIdx.x == 64) rowptr[NROWS] = TOTSLOTS;
    __syncthreads();
    for (int e = beg + (int)threadIdx.x; e < end; e += 256) {
        int2 pk = staging[e];
        int off = pk.x >> 17;
        int dst = rp[off] + atomicAdd(&fillr[off], 1);
        unsigned int src = (unsigned int)(pk.x & 0x1FFFF);
        unsigned int bv = f2b(__int_as_float(pk.y)) & 0x7FFFu;
        csr4[dst] = (src << 15) | bv;
    }
}

// ---------------- propagation: half-wave per edge, ushort2 (uint) packed lanes ----------------
// 32 lanes cover a 64-dim row at 4B/lane; the wave's two halves process edges
// e+0 / e+1 concurrently (even/odd partial sums merged by shfl_xor(32) at the end).
// Halves VALU issues per edge vs 2B/lane (R13: VALUBusy 72% = issue-bound).
__global__ void __launch_bounds__(256) agg_kernel(
        const unsigned short* __restrict__ uprev, const unsigned short* __restrict__ iprev,
        unsigned short* __restrict__ unext, unsigned short* __restrict__ inext,
        const float* __restrict__ di, const float* __restrict__ dj,
        const int* __restrict__ rowptr, const unsigned int* __restrict__ csr4) {
    int wid = (blockIdx.x * 256 + threadIdx.x) >> 6;
    int lane = threadIdx.x & 63;
    if (wid >= NROWS) return;
    int half = lane >> 5;
    unsigned int dp = (unsigned int)(lane & 31);   // dim-pair index
    const unsigned int* selfU;
    const unsigned int* srcU;
    unsigned int* dstU;
    float dscale;
    unsigned int r32;
    if (wid < U_NUM) {
        r32 = (unsigned int)wid;
        selfU = (const unsigned int*)uprev;
        srcU  = (const unsigned int*)iprev;
        dstU  = (unsigned int*)unext;
        dscale = di[wid];
    } else {
        r32 = (unsigned int)(wid - U_NUM);
        selfU = (const unsigned int*)iprev;
        srcU  = (const unsigned int*)uprev;
        dstU  = (unsigned int*)inext;
        dscale = dj[wid - U_NUM];
    }
    int beg = rowptr[wid], end = rowptr[wid + 1];
    unsigned int selfIdx = (r32 << 5) | dp;
    float accx, accy;
    {
        unsigned int s = selfU[selfIdx];
        float sx = b2f((unsigned short)(s & 0xFFFFu));
        float sy = b2f((unsigned short)(s >> 16));
        accx = (half == 0) ? sx * dscale : 0.0f;
        accy = (half == 0) ? sy * dscale : 0.0f;
    }
    int e = beg;
    for (; e + 8 <= end; e += 8) {
        unsigned int pk[4], g[4];
#pragma unroll
        for (int k = 0; k < 4; k++) pk[k] = csr4[e + 2 * k + half];
#pragma unroll
        for (int k = 0; k < 4; k++) g[k] = srcU[((pk[k] >> 15) << 5) | dp];
#pragma unroll
        for (int k = 0; k < 4; k++) {
            float w = b2f((unsigned short)(pk[k] & 0x7FFFu));
            accx = fmaf(w, b2f((unsigned short)(g[k] & 0xFFFFu)), accx);
            accy = fmaf(w, b2f((unsigned short)(g[k] >> 16)), accy);
        }
    }
    for (; e < end; e += 2) {
        int idx = e + half;
        if (idx < end) {
            unsigned int pk = csr4[idx];
            unsigned int g = srcU[((pk >> 15) << 5) | dp];
            float w = b2f((unsigned short)(pk & 0x7FFFu));
            accx = fmaf(w, b2f((unsigned short)(g & 0xFFFFu)), accx);
            accy = fmaf(w, b2f((unsigned short)(g >> 16)), accy);
        }
    }
    accx += __shfl_xor(accx, 32);
    accy += __shfl_xor(accy, 32);
    if (half == 0) {
        unsigned int o = ((unsigned int)f2b(accy) << 16) | (unsigned int)f2b(accx);
        dstU[selfIdx] = o;
    }
}

// ---------------- BPR head ----------------
__global__ void __launch_bounds__(256) batch_kernel(
        const float* __restrict__ u0f, const float* __restrict__ i0f,
        const unsigned short* __restrict__ u1, const unsigned short* __restrict__ u2,
        const unsigned short* __restrict__ u3,
        const unsigned short* __restrict__ i1, const unsigned short* __restrict__ i2,
        const unsigned short* __restrict__ i3,
        const int* __restrict__ user, const int* __restrict__ ita, const int* __restrict__ itb,
        float* __restrict__ out, float* __restrict__ ls, float* __restrict__ l2a) {
    int wid = (blockIdx.x * 256 + threadIdx.x) >> 6;
    int lane = threadIdx.x & 63;
    if (wid >= BATCH) return;
    size_t uo = (size_t)user[wid] * FCT + lane;
    size_t ao = (size_t)ita[wid] * FCT + lane;
    size_t bo = (size_t)itb[wid] * FCT + lane;

    float pi, pj, l2;
    {
        float ue = u0f[uo], ie = i0f[ao], je = i0f[bo];
        pi = ue * ie; pj = ue * je; l2 = ue * ue + ie * ie + je * je;
    }
    const unsigned short* Ut[3] = {u1, u2, u3};
    const unsigned short* It[3] = {i1, i2, i3};
#pragma unroll
    for (int l = 0; l < 3; l++) {
        float ue = b2f(Ut[l][uo]), ie = b2f(It[l][ao]), je = b2f(It[l][bo]);
        pi += ue * ie;
        pj += ue * je;
        l2 += ue * ue + ie * ie + je * je;
    }
#pragma unroll
    for (int off = 32; off; off >>= 1) {
        pi += __shfl_xor(pi, off);
        pj += __shfl_xor(pj, off);
        l2 += __shfl_xor(l2, off);
    }
    if (lane == 0) {
        out[wid] = pi;
        out[BATCH + wid] = pj;
        float x = pi - pj;
        ls[wid] = fminf(x, 0.0f) - log1pf(expf(-fabsf(x)));
        l2a[wid] = 0.01f * l2;
    }
}

__global__ void final_kernel(const float* __restrict__ ls, const float* __restrict__ l2a,
                             float* __restrict__ out) {
    __shared__ float s1[256], s2[256];
    int t = threadIdx.x;
    float a = 0.f, b = 0.f;
    for (int i = t; i < BATCH; i += 256) {
        a += ls[i];
        b += l2a[i];
    }
    s1[t] = a;
    s2[t] = b;
    __syncthreads();
    for (int off = 128; off; off >>= 1) {
        if (t < off) {
            s1[t] += s1[t + off];
            s2[t] += s2[t + off];
        }
        __syncthreads();
    }
    if (t == 0) {
        float loss2 = -s1[0] / (float)BATCH;
        float l2m = s2[0] / (float)BATCH;
        out[2 * BATCH] = loss2 + l2m;
        out[2 * BATCH + 1] = loss2;
    }
}

// ---------------- launch ----------------
extern "C" void kernel_launch(void* const* d_in, const int* in_sizes, int n_in,
                              void* d_out, int out_size, void* d_ws, size_t ws_size,
                              hipStream_t stream) {
    const float* u0f = (const float*)d_in[0];
    const float* i0f = (const float*)d_in[1];
    const float* di  = (const float*)d_in[2];
    const float* dj  = (const float*)d_in[3];
    const float* vui = (const float*)d_in[4];
    const float* viu = (const float*)d_in[5];
    const int*   eu  = (const int*)d_in[6];
    const int*   ei  = (const int*)d_in[7];
    const int*   usr = (const int*)d_in[8];
    const int*   ita = (const int*)d_in[9];
    const int*   itb = (const int*)d_in[10];
    float* out = (float*)d_out;

    char* p = (char*)d_ws;
    auto alloc = [&](size_t bytes) -> char* {
        char* r = p;
        p += (bytes + 255) & ~(size_t)255;
        return r;
    };
    unsigned short* u0b = (unsigned short*)alloc((size_t)U_NUM * FCT * 2);
    unsigned short* u1b = (unsigned short*)alloc((size_t)U_NUM * FCT * 2);
    unsigned short* i0b = (unsigned short*)alloc((size_t)I_NUM * FCT * 2);
    unsigned short* i1b = (unsigned short*)alloc((size_t)I_NUM * FCT * 2);
    unsigned int* csr4 = (unsigned int*)alloc((size_t)TOTSLOTS * 4);   // 25.6 MB
    int2* staging = (int2*)alloc((size_t)TOTSLOTS * 8);                // 51.2 MB
    int* rowptr  = (int*)alloc((size_t)(NROWS + 1) * 4);
    int* bcnt8   = (int*)alloc((size_t)8 * NBUCK * 4);
    int* bbase   = (int*)alloc((size_t)(NBUCK + 1) * 4);
    int* cntmat  = (int*)alloc((size_t)8 * SUBS * NQ * 4);
    int* basemat = (int*)alloc((size_t)8 * SUBS * NQ * 4);
    float* ls    = (float*)alloc((size_t)BATCH * 4);
    float* l2a   = (float*)alloc((size_t)BATCH * 4);
    // overlay levels 2,3 on staging (dead after rsort; written by later agg launches)
    unsigned short* u2b = (unsigned short*)staging;
    unsigned short* u3b = u2b + (size_t)U_NUM * FCT;
    unsigned short* i2b = u3b + (size_t)U_NUM * FCT;
    unsigned short* i3b = i2b + (size_t)I_NUM * FCT;

    hipMemsetAsync(bcnt8, 0, (size_t)8 * NBUCK * 4, stream);

    conv_kernel<<<(U_NUM * FCT / 4 + 255) / 256, 256, 0, stream>>>(u0f, u0b, U_NUM * FCT / 4);
    conv_kernel<<<(I_NUM * FCT / 4 + 255) / 256, 256, 0, stream>>>(i0f, i0b, I_NUM * FCT / 4);

    bhist_kernel<<<512, 256, 0, stream>>>(eu, ei, bcnt8);
    bscan_kernel<<<1, 256, 0, stream>>>(bcnt8, bbase);

    countA_kernel<<<2048, 256, 0, stream>>>(eu, ei, cntmat);
    bscan2_kernel<<<NBUCK, 256, 0, stream>>>(cntmat, bbase, basemat);
    scatterB_kernel<<<2048, 256, 0, stream>>>(eu, ei, vui, viu, cntmat, basemat, staging);
    rsort_kernel<<<NBUCK, 256, 0, stream>>>(bbase, staging, csr4, rowptr);

    int aggGrid = (NROWS * 64) / 256 + 1;
    agg_kernel<<<aggGrid, 256, 0, stream>>>(u0b, i0b, u1b, i1b, di, dj, rowptr, csr4);
    agg_kernel<<<aggGrid, 256, 0, stream>>>(u1b, i1b, u2b, i2b, di, dj, rowptr, csr4);
    agg_kernel<<<aggGrid, 256, 0, stream>>>(u2b, i2b, u3b, i3b, di, dj, rowptr, csr4);

    batch_kernel<<<(BATCH * 64) / 256, 256, 0, stream>>>(u0f, i0f, u1b, u2b, u3b,
                                                         i1b, i2b, i3b,
                                                         usr, ita, itb, out, ls, l2a);
    final_kernel<<<1, 256, 0, stream>>>(ls, l2a, out);
}

// Round 15
// 592.512 us; speedup vs baseline: 1.4349x; 1.0693x over previous
//
#include <hip/hip_runtime.h>

#define U_NUM   100000
#define I_NUM   50000
#define FCT     64
#define NEDGE   3200000
#define BATCH   16384
#define NROWS   (U_NUM + I_NUM)      // 150000
#define TOTSLOTS (2 * NEDGE)         // 6400000

#define BSH 6                        // 64 rows per bucket
#define NBU 1563                     // ceil(100000/64)
#define NBI 782                      // ceil(50000/64)
#define NBUCK (NBU + NBI)            // 2345
#define NQ   294                     // ceil(NBUCK/8) buckets per class
#define SUBS 256                     // blocks per class in scatter grid
#define BUFSZ 4096                   // LDS payload buffer (expected fill 3125)

__device__ __forceinline__ unsigned short f2b(float f) {
    unsigned int x = __float_as_uint(f);
    unsigned int r = (x + 0x7FFFu + ((x >> 16) & 1u)) >> 16;   // RNE
    return (unsigned short)r;
}
__device__ __forceinline__ float b2f(unsigned short u) {
    return __uint_as_float(((unsigned int)u) << 16);
}

// ---------------- fp32 -> bf16 table conversion ----------------
__global__ void conv_kernel(const float* __restrict__ in, unsigned short* __restrict__ out, int n4) {
    int t = blockIdx.x * blockDim.x + threadIdx.x;
    if (t >= n4) return;
    float4 v = *reinterpret_cast<const float4*>(in + (size_t)t * 4);
    ushort4 o;
    o.x = f2b(v.x); o.y = f2b(v.y); o.z = f2b(v.z); o.w = f2b(v.w);
    *reinterpret_cast<ushort4*>(out + (size_t)t * 4) = o;
}

// ---------------- single-sweep per-(sub,bucket) count (replaces bhist + countA) ----------------
// 256 blocks; block sub sweeps EXACTLY scatterB's slice once, histograms all buckets
// in LDS, writes its count row coalesced. Edge reads for counting: 1x (was 1x + 8x).
__global__ void __launch_bounds__(256) count256_kernel(const int* __restrict__ eu,
                                                       const int* __restrict__ ei,
                                                       int* __restrict__ cntmat256) {
    __shared__ int lcnt[NBUCK];
    for (int k = threadIdx.x; k < NBUCK; k += 256) lcnt[k] = 0;
    __syncthreads();
    int sub = blockIdx.x;
    for (int t = sub * 256 + (int)threadIdx.x; t < NEDGE; t += SUBS * 256) {
        int u = eu[t];
        int i = ei[t];
        atomicAdd(&lcnt[u >> BSH], 1);
        atomicAdd(&lcnt[NBU + (i >> BSH)], 1);
    }
    __syncthreads();
    int* row = cntmat256 + (size_t)sub * NBUCK;
    for (int k = threadIdx.x; k < NBUCK; k += 256) row[k] = lcnt[k];
}

// ---------------- per-bucket scan over 256 subs -> localpfx + bucket total ----------------
__global__ void __launch_bounds__(256) bscan2_kernel(const int* __restrict__ cntmat256,
                                                     int* __restrict__ localpfx,
                                                     int* __restrict__ btot) {
    __shared__ int ws[4];
    int b = blockIdx.x;
    int t = threadIdx.x;
    int c = cntmat256[(size_t)t * NBUCK + b];
    int inc = c;
#pragma unroll
    for (int o = 1; o < 64; o <<= 1) {
        int x = __shfl_up(inc, o);
        if ((t & 63) >= o) inc += x;
    }
    if ((t & 63) == 63) ws[t >> 6] = inc;
    __syncthreads();
    int carry = 0;
#pragma unroll
    for (int w = 0; w < 4; w++) {
        if ((t >> 6) > w) carry += ws[w];
    }
    localpfx[(size_t)b * 256 + t] = carry + inc - c;   // exclusive prefix within bucket
    if (t == 255) btot[b] = carry + inc;               // bucket total
}

// ---------------- single-block exclusive scan over bucket totals -> bbase ----------------
__global__ void bscan_kernel(const int* __restrict__ btot, int* __restrict__ bbase) {
    __shared__ int s[256];
    int t = threadIdx.x;
    int v[10];                          // 256*10 = 2560 >= NBUCK
    int tot = 0;
#pragma unroll
    for (int k = 0; k < 10; k++) {
        int idx = t * 10 + k;
        v[k] = (idx < NBUCK) ? btot[idx] : 0;
        tot += v[k];
    }
    s[t] = tot;
    __syncthreads();
    for (int off = 1; off < 256; off <<= 1) {
        int x = (t >= off) ? s[t - off] : 0;
        __syncthreads();
        s[t] += x;
        __syncthreads();
    }
    int p = s[t] - tot;
#pragma unroll
    for (int k = 0; k < 10; k++) {
        int idx = t * 10 + k;
        if (idx < NBUCK) bbase[idx] = p;
        p += v[k];
    }
    if (t == 255) bbase[NBUCK] = TOTSLOTS;
}

// ---------------- multisplit scatter: LDS-buffered rank-scatter + coalesced flush ----------------
__global__ void __launch_bounds__(256) scatterB_kernel(const int* __restrict__ eu,
                                                       const int* __restrict__ ei,
                                                       const float* __restrict__ vui,
                                                       const float* __restrict__ viu,
                                                       const int* __restrict__ cntmat256,
                                                       const int* __restrict__ localpfx,
                                                       const int* __restrict__ bbase,
                                                       int2* __restrict__ staging) {
    __shared__ int lofs[NQ + 1];
    __shared__ int lbase[NQ];
    __shared__ int lrank[NQ];
    __shared__ int2 lbuf[BUFSZ];     // 32 KB
    int cls = blockIdx.x & 7;
    int sub = blockIdx.x >> 3;
    for (int k = threadIdx.x; k < NQ; k += 256) {
        int b = k * 8 + cls;
        if (b < NBUCK) {
            lbase[k] = bbase[b] + localpfx[(size_t)b * 256 + sub];
            lofs[k + 1] = cntmat256[(size_t)sub * NBUCK + b];
        } else {
            lbase[k] = 0;
            lofs[k + 1] = 0;
        }
        lrank[k] = 0;
    }
    if (threadIdx.x == 0) lofs[0] = 0;
    __syncthreads();
    if (threadIdx.x < 64) {
        int carry = 0;
        for (int c = 0; c < 5; c++) {
            int idx = c * 64 + (int)threadIdx.x + 1;
            int v = (idx <= NQ) ? lofs[idx] : 0;
            int inc = v;
#pragma unroll
            for (int o = 1; o < 64; o <<= 1) {
                int x = __shfl_up(inc, o);
                if ((int)threadIdx.x >= o) inc += x;
            }
            if (idx <= NQ) lofs[idx] = carry + inc;
            carry += __shfl(inc, 63);
        }
    }
    __syncthreads();
    int total = lofs[NQ];
    for (int t = sub * 256 + (int)threadIdx.x; t < NEDGE; t += SUBS * 256) {
        int u = eu[t];
        int i = ei[t];
        int bu = u >> BSH;
        if ((bu & 7) == cls) {
            int q = bu >> 3;
            int r = atomicAdd(&lrank[q], 1);
            int2 pay = make_int2(((u & 63) << 17) | i, __float_as_int(vui[t]));
            int pos = lofs[q] + r;
            if (pos < BUFSZ) lbuf[pos] = pay;
            else staging[lbase[q] + r] = pay;
        }
        int bid = NBU + (i >> BSH);
        if ((bid & 7) == cls) {
            int q = bid >> 3;
            int r = atomicAdd(&lrank[q], 1);
            int2 pay = make_int2(((i & 63) << 17) | u, __float_as_int(viu[t]));
            int pos = lofs[q] + r;
            if (pos < BUFSZ) lbuf[pos] = pay;
            else staging[lbase[q] + r] = pay;
        }
    }
    __syncthreads();
    int fl = min(total, BUFSZ);
    for (int t = threadIdx.x; t < fl; t += 256) {
        int lo = 0, hi = NQ;
        while (hi - lo > 1) {
            int mid = (lo + hi) >> 1;
            if (lofs[mid] <= t) lo = mid; else hi = mid;
        }
        staging[lbase[lo] + (t - lofs[lo])] = lbuf[t];
    }
}

// ---------------- phase B: row counts -> rowptr -> row-ordered PACKED csr ----------------
__global__ void __launch_bounds__(256) rsort_kernel(const int* __restrict__ bbase,
                                                    const int2* __restrict__ staging,
                                                    unsigned int* __restrict__ csr4,
                                                    int* __restrict__ rowptr) {
    __shared__ int fillr[64];
    __shared__ int rp[64];
    int b = blockIdx.x;
    int gRowBase, rows;
    if (b < NBU) {
        gRowBase = b << BSH;
        rows = min(64, U_NUM - gRowBase);
    } else {
        int rb = (b - NBU) << BSH;
        gRowBase = U_NUM + rb;
        rows = min(64, I_NUM - rb);
    }
    if (threadIdx.x < 64) fillr[threadIdx.x] = 0;
    __syncthreads();
    int beg = bbase[b], end = bbase[b + 1];
    for (int e = beg + (int)threadIdx.x; e < end; e += 256) {
        int off = staging[e].x >> 17;
        atomicAdd(&fillr[off], 1);
    }
    __syncthreads();
    if (threadIdx.x < 64) {
        int c = fillr[threadIdx.x];
        int inc = c;
#pragma unroll
        for (int o = 1; o < 64; o <<= 1) {
            int x = __shfl_up(inc, o);
            if ((int)threadIdx.x >= o) inc += x;
        }
        int excl = beg + inc - c;
        rp[threadIdx.x] = excl;
        if ((int)threadIdx.x < rows) rowptr[gRowBase + threadIdx.x] = excl;
        fillr[threadIdx.x] = 0;
    }
    if (b == 0 && threadIdx.x == 64) rowptr[NROWS] = TOTSLOTS;
    __syncthreads();
    for (int e = beg + (int)threadIdx.x; e < end; e += 256) {
        int2 pk = staging[e];
        int off = pk.x >> 17;
        int dst = rp[off] + atomicAdd(&fillr[off], 1);
        unsigned int src = (unsigned int)(pk.x & 0x1FFFF);
        unsigned int bv = f2b(__int_as_float(pk.y)) & 0x7FFFu;
        csr4[dst] = (src << 15) | bv;
    }
}

// ---------------- propagation: half-wave per edge, ushort2 (uint) packed lanes ----------------
__global__ void __launch_bounds__(256) agg_kernel(
        const unsigned short* __restrict__ uprev, const unsigned short* __restrict__ iprev,
        unsigned short* __restrict__ unext, unsigned short* __restrict__ inext,
        const float* __restrict__ di, const float* __restrict__ dj,
        const int* __restrict__ rowptr, const unsigned int* __restrict__ csr4) {
    int wid = (blockIdx.x * 256 + threadIdx.x) >> 6;
    int lane = threadIdx.x & 63;
    if (wid >= NROWS) return;
    int half = lane >> 5;
    unsigned int dp = (unsigned int)(lane & 31);   // dim-pair index
    const unsigned int* selfU;
    const unsigned int* srcU;
    unsigned int* dstU;
    float dscale;
    unsigned int r32;
    if (wid < U_NUM) {
        r32 = (unsigned int)wid;
        selfU = (const unsigned int*)uprev;
        srcU  = (const unsigned int*)iprev;
        dstU  = (unsigned int*)unext;
        dscale = di[wid];
    } else {
        r32 = (unsigned int)(wid - U_NUM);
        selfU = (const unsigned int*)iprev;
        srcU  = (const unsigned int*)uprev;
        dstU  = (unsigned int*)inext;
        dscale = dj[wid - U_NUM];
    }
    int beg = rowptr[wid], end = rowptr[wid + 1];
    unsigned int selfIdx = (r32 << 5) | dp;
    float accx, accy;
    {
        unsigned int s = selfU[selfIdx];
        float sx = b2f((unsigned short)(s & 0xFFFFu));
        float sy = b2f((unsigned short)(s >> 16));
        accx = (half == 0) ? sx * dscale : 0.0f;
        accy = (half == 0) ? sy * dscale : 0.0f;
    }
    int e = beg;
    for (; e + 8 <= end; e += 8) {
        unsigned int pk[4], g[4];
#pragma unroll
        for (int k = 0; k < 4; k++) pk[k] = csr4[e + 2 * k + half];
#pragma unroll
        for (int k = 0; k < 4; k++) g[k] = srcU[((pk[k] >> 15) << 5) | dp];
#pragma unroll
        for (int k = 0; k < 4; k++) {
            float w = b2f((unsigned short)(pk[k] & 0x7FFFu));
            accx = fmaf(w, b2f((unsigned short)(g[k] & 0xFFFFu)), accx);
            accy = fmaf(w, b2f((unsigned short)(g[k] >> 16)), accy);
        }
    }
    for (; e < end; e += 2) {
        int idx = e + half;
        if (idx < end) {
            unsigned int pk = csr4[idx];
            unsigned int g = srcU[((pk >> 15) << 5) | dp];
            float w = b2f((unsigned short)(pk & 0x7FFFu));
            accx = fmaf(w, b2f((unsigned short)(g & 0xFFFFu)), accx);
            accy = fmaf(w, b2f((unsigned short)(g >> 16)), accy);
        }
    }
    accx += __shfl_xor(accx, 32);
    accy += __shfl_xor(accy, 32);
    if (half == 0) {
        unsigned int o = ((unsigned int)f2b(accy) << 16) | (unsigned int)f2b(accx);
        dstU[selfIdx] = o;
    }
}

// ---------------- BPR head ----------------
__global__ void __launch_bounds__(256) batch_kernel(
        const float* __restrict__ u0f, const float* __restrict__ i0f,
        const unsigned short* __restrict__ u1, const unsigned short* __restrict__ u2,
        const unsigned short* __restrict__ u3,
        const unsigned short* __restrict__ i1, const unsigned short* __restrict__ i2,
        const unsigned short* __restrict__ i3,
        const int* __restrict__ user, const int* __restrict__ ita, const int* __restrict__ itb,
        float* __restrict__ out, float* __restrict__ ls, float* __restrict__ l2a) {
    int wid = (blockIdx.x * 256 + threadIdx.x) >> 6;
    int lane = threadIdx.x & 63;
    if (wid >= BATCH) return;
    size_t uo = (size_t)user[wid] * FCT + lane;
    size_t ao = (size_t)ita[wid] * FCT + lane;
    size_t bo = (size_t)itb[wid] * FCT + lane;

    float pi, pj, l2;
    {
        float ue = u0f[uo], ie = i0f[ao], je = i0f[bo];
        pi = ue * ie; pj = ue * je; l2 = ue * ue + ie * ie + je * je;
    }
    const unsigned short* Ut[3] = {u1, u2, u3};
    const unsigned short* It[3] = {i1, i2, i3};
#pragma unroll
    for (int l = 0; l < 3; l++) {
        float ue = b2f(Ut[l][uo]), ie = b2f(It[l][ao]), je = b2f(It[l][bo]);
        pi += ue * ie;
        pj += ue * je;
        l2 += ue * ue + ie * ie + je * je;
    }
#pragma unroll
    for (int off = 32; off; off >>= 1) {
        pi += __shfl_xor(pi, off);
        pj += __shfl_xor(pj, off);
        l2 += __shfl_xor(l2, off);
    }
    if (lane == 0) {
        out[wid] = pi;
        out[BATCH + wid] = pj;
        float x = pi - pj;
        ls[wid] = fminf(x, 0.0f) - log1pf(expf(-fabsf(x)));
        l2a[wid] = 0.01f * l2;
    }
}

__global__ void final_kernel(const float* __restrict__ ls, const float* __restrict__ l2a,
                             float* __restrict__ out) {
    __shared__ float s1[256], s2[256];
    int t = threadIdx.x;
    float a = 0.f, b = 0.f;
    for (int i = t; i < BATCH; i += 256) {
        a += ls[i];
        b += l2a[i];
    }
    s1[t] = a;
    s2[t] = b;
    __syncthreads();
    for (int off = 128; off; off >>= 1) {
        if (t < off) {
            s1[t] += s1[t + off];
            s2[t] += s2[t + off];
        }
        __syncthreads();
    }
    if (t == 0) {
        float loss2 = -s1[0] / (float)BATCH;
        float l2m = s2[0] / (float)BATCH;
        out[2 * BATCH] = loss2 + l2m;
        out[2 * BATCH + 1] = loss2;
    }
}

// ---------------- launch ----------------
extern "C" void kernel_launch(void* const* d_in, const int* in_sizes, int n_in,
                              void* d_out, int out_size, void* d_ws, size_t ws_size,
                              hipStream_t stream) {
    const float* u0f = (const float*)d_in[0];
    const float* i0f = (const float*)d_in[1];
    const float* di  = (const float*)d_in[2];
    const float* dj  = (const float*)d_in[3];
    const float* vui = (const float*)d_in[4];
    const float* viu = (const float*)d_in[5];
    const int*   eu  = (const int*)d_in[6];
    const int*   ei  = (const int*)d_in[7];
    const int*   usr = (const int*)d_in[8];
    const int*   ita = (const int*)d_in[9];
    const int*   itb = (const int*)d_in[10];
    float* out = (float*)d_out;

    char* p = (char*)d_ws;
    auto alloc = [&](size_t bytes) -> char* {
        char* r = p;
        p += (bytes + 255) & ~(size_t)255;
        return r;
    };
    unsigned short* u0b = (unsigned short*)alloc((size_t)U_NUM * FCT * 2);
    unsigned short* u1b = (unsigned short*)alloc((size_t)U_NUM * FCT * 2);
    unsigned short* i0b = (unsigned short*)alloc((size_t)I_NUM * FCT * 2);
    unsigned short* i1b = (unsigned short*)alloc((size_t)I_NUM * FCT * 2);
    unsigned int* csr4 = (unsigned int*)alloc((size_t)TOTSLOTS * 4);   // 25.6 MB
    int2* staging = (int2*)alloc((size_t)TOTSLOTS * 8);                // 51.2 MB
    int* rowptr    = (int*)alloc((size_t)(NROWS + 1) * 4);
    int* cntmat256 = (int*)alloc((size_t)SUBS * NBUCK * 4);            // 2.4 MB
    int* localpfx  = (int*)alloc((size_t)NBUCK * SUBS * 4);            // 2.4 MB
    int* btot      = (int*)alloc((size_t)NBUCK * 4);
    int* bbase     = (int*)alloc((size_t)(NBUCK + 1) * 4);
    float* ls      = (float*)alloc((size_t)BATCH * 4);
    float* l2a     = (float*)alloc((size_t)BATCH * 4);
    // overlay levels 2,3 on staging (dead after rsort; written by later agg launches)
    unsigned short* u2b = (unsigned short*)staging;
    unsigned short* u3b = u2b + (size_t)U_NUM * FCT;
    unsigned short* i2b = u3b + (size_t)U_NUM * FCT;
    unsigned short* i3b = i2b + (size_t)I_NUM * FCT;

    conv_kernel<<<(U_NUM * FCT / 4 + 255) / 256, 256, 0, stream>>>(u0f, u0b, U_NUM * FCT / 4);
    conv_kernel<<<(I_NUM * FCT / 4 + 255) / 256, 256, 0, stream>>>(i0f, i0b, I_NUM * FCT / 4);

    count256_kernel<<<SUBS, 256, 0, stream>>>(eu, ei, cntmat256);
    bscan2_kernel<<<NBUCK, 256, 0, stream>>>(cntmat256, localpfx, btot);
    bscan_kernel<<<1, 256, 0, stream>>>(btot, bbase);

    scatterB_kernel<<<2048, 256, 0, stream>>>(eu, ei, vui, viu, cntmat256, localpfx, bbase, staging);
    rsort_kernel<<<NBUCK, 256, 0, stream>>>(bbase, staging, csr4, rowptr);

    int aggGrid = (NROWS * 64) / 256 + 1;
    agg_kernel<<<aggGrid, 256, 0, stream>>>(u0b, i0b, u1b, i1b, di, dj, rowptr, csr4);
    agg_kernel<<<aggGrid, 256, 0, stream>>>(u1b, i1b, u2b, i2b, di, dj, rowptr, csr4);
    agg_kernel<<<aggGrid, 256, 0, stream>>>(u2b, i2b, u3b, i3b, di, dj, rowptr, csr4);

    batch_kernel<<<(BATCH * 64) / 256, 256, 0, stream>>>(u0f, i0f, u1b, u2b, u3b,
                                                         i1b, i2b, i3b,
                                                         usr, ita, itb, out, ls, l2a);
    final_kernel<<<1, 256, 0, stream>>>(ls, l2a, out);
}